// Round 1
// baseline (179.561 us; speedup 1.0000x reference)
//
#include <hip/hip_runtime.h>

#define EPSILON 0.05f
#define NSLOTS 64

// One wave (64 lanes) per ray. Lanes do strided float4 loads across the
// 1024-sample row (fully coalesced: lane i reads float4 at index lane+64k).
// Wave shuffle-reduction -> lane 0 does masked atomicAdd into 64 partial
// slots (slot = ray & 63) to avoid same-address contention.
__global__ __launch_bounds__(256) void sight_near_loss_kernel(
    const float* __restrict__ ray_depth,   // [N]
    const float* __restrict__ z_vals,      // [N, S]
    const float* __restrict__ weights,     // [N, S]
    const int*   __restrict__ ray_mask,    // [N] (0/1)
    float* __restrict__ partials,          // [3*NSLOTS]: empty | near | nmask
    int n_rays, int S)
{
    const int wave = threadIdx.x >> 6;
    const int lane = threadIdx.x & 63;
    const int r = blockIdx.x * 4 + wave;
    if (r >= n_rays) return;

    const float d  = ray_depth[r];
    const float lo = d - EPSILON;
    const float hi = d + EPSILON;

    const float4* z4 = (const float4*)(z_vals  + (size_t)r * S);
    const float4* w4 = (const float4*)(weights + (size_t)r * S);
    const int n4 = S >> 2;

    float empty = 0.0f;   // sum w^2 where z < lo
    float wnear = 0.0f;   // sum w   where lo <= z < hi

    for (int k = lane; k < n4; k += 64) {
        const float4 z = z4[k];
        const float4 w = w4[k];
        empty += (z.x < lo) ? w.x * w.x : 0.0f;
        empty += (z.y < lo) ? w.y * w.y : 0.0f;
        empty += (z.z < lo) ? w.z * w.z : 0.0f;
        empty += (z.w < lo) ? w.w * w.w : 0.0f;
        wnear += (z.x >= lo && z.x < hi) ? w.x : 0.0f;
        wnear += (z.y >= lo && z.y < hi) ? w.y : 0.0f;
        wnear += (z.z >= lo && z.z < hi) ? w.z : 0.0f;
        wnear += (z.w >= lo && z.w < hi) ? w.w : 0.0f;
    }

    // wave-64 butterfly reduction
    #pragma unroll
    for (int off = 32; off > 0; off >>= 1) {
        empty += __shfl_down(empty, off, 64);
        wnear += __shfl_down(wnear, off, 64);
    }

    if (lane == 0 && ray_mask[r] != 0) {
        const int slot = r & (NSLOTS - 1);
        const float t = 1.0f - wnear;
        atomicAdd(&partials[slot],              empty);
        atomicAdd(&partials[NSLOTS + slot],     t * t);
        atomicAdd(&partials[2 * NSLOTS + slot], 1.0f);
    }
}

__global__ void sight_near_finalize_kernel(
    const float* __restrict__ partials, float* __restrict__ out)
{
    const int lane = threadIdx.x;  // 64 threads
    float e = partials[lane];
    float n = partials[NSLOTS + lane];
    float m = partials[2 * NSLOTS + lane];
    #pragma unroll
    for (int off = 32; off > 0; off >>= 1) {
        e += __shfl_down(e, off, 64);
        n += __shfl_down(n, off, 64);
        m += __shfl_down(m, off, 64);
    }
    if (lane == 0) {
        out[0] = e / m;   // loss_empty
        out[1] = n / m;   // loss_near
    }
}

extern "C" void kernel_launch(void* const* d_in, const int* in_sizes, int n_in,
                              void* d_out, int out_size, void* d_ws, size_t ws_size,
                              hipStream_t stream) {
    const float* ray_depth = (const float*)d_in[0];
    const float* z_vals    = (const float*)d_in[1];
    const float* weights   = (const float*)d_in[2];
    const int*   ray_mask  = (const int*)d_in[3];

    const int n_rays = in_sizes[0];                // ray_depth is [N,1]
    const int S      = in_sizes[1] / n_rays;       // 1024

    float* partials = (float*)d_ws;
    hipMemsetAsync(partials, 0, 3 * NSLOTS * sizeof(float), stream);

    const int blocks = (n_rays + 3) / 4;           // 4 waves per block
    sight_near_loss_kernel<<<blocks, 256, 0, stream>>>(
        ray_depth, z_vals, weights, ray_mask, partials, n_rays, S);
    sight_near_finalize_kernel<<<1, 64, 0, stream>>>(partials, (float*)d_out);
}

// Round 2
// 167.409 us; speedup vs baseline: 1.0726x; 1.0726x over previous
//
#include <hip/hip_runtime.h>

#define EPSILON 0.05f
#define NSLOTS 64

// One wave (64 lanes) per ray, S=1024 specialized. Each lane loads 4
// float4 of z and 4 float4 of w at lane-strided indices (lane + 64k) --
// all 8 global_load_dwordx4 are issued before any use, so 8 loads are in
// flight per wave (vs 2 in the runtime-S loop version). Fully coalesced:
// each load instruction covers 1 KiB contiguous.
template <int S>
__global__ __launch_bounds__(256) void sight_near_loss_kernel(
    const float* __restrict__ ray_depth,   // [N]
    const float* __restrict__ z_vals,      // [N, S]
    const float* __restrict__ weights,     // [N, S]
    const int*   __restrict__ ray_mask,    // [N] (0/1)
    float* __restrict__ partials,          // [3*NSLOTS]: empty | near | nmask
    int n_rays)
{
    const int wave = threadIdx.x >> 6;
    const int lane = threadIdx.x & 63;
    const int r = blockIdx.x * 4 + wave;
    if (r >= n_rays) return;

    const float d  = ray_depth[r];
    const float lo = d - EPSILON;
    const float hi = d + EPSILON;

    const float4* z4 = (const float4*)(z_vals  + (size_t)r * S);
    const float4* w4 = (const float4*)(weights + (size_t)r * S);
    constexpr int n4 = S / 4;          // 256
    constexpr int IT = n4 / 64;        // 4 float4 per lane per stream

    float4 z[IT], w[IT];
    #pragma unroll
    for (int k = 0; k < IT; ++k) z[k] = z4[lane + 64 * k];
    #pragma unroll
    for (int k = 0; k < IT; ++k) w[k] = w4[lane + 64 * k];

    float empty = 0.0f;   // sum w^2 where z < lo
    float wnear = 0.0f;   // sum w   where lo <= z < hi
    #pragma unroll
    for (int k = 0; k < IT; ++k) {
        empty += (z[k].x < lo) ? w[k].x * w[k].x : 0.0f;
        empty += (z[k].y < lo) ? w[k].y * w[k].y : 0.0f;
        empty += (z[k].z < lo) ? w[k].z * w[k].z : 0.0f;
        empty += (z[k].w < lo) ? w[k].w * w[k].w : 0.0f;
        wnear += (z[k].x >= lo && z[k].x < hi) ? w[k].x : 0.0f;
        wnear += (z[k].y >= lo && z[k].y < hi) ? w[k].y : 0.0f;
        wnear += (z[k].z >= lo && z[k].z < hi) ? w[k].z : 0.0f;
        wnear += (z[k].w >= lo && z[k].w < hi) ? w[k].w : 0.0f;
    }

    // wave-64 reduction
    #pragma unroll
    for (int off = 32; off > 0; off >>= 1) {
        empty += __shfl_down(empty, off, 64);
        wnear += __shfl_down(wnear, off, 64);
    }

    if (lane == 0 && ray_mask[r] != 0) {
        const int slot = r & (NSLOTS - 1);
        const float t = 1.0f - wnear;
        atomicAdd(&partials[slot],              empty);
        atomicAdd(&partials[NSLOTS + slot],     t * t);
        atomicAdd(&partials[2 * NSLOTS + slot], 1.0f);
    }
}

// Generic fallback (runtime S), same structure as R0.
__global__ __launch_bounds__(256) void sight_near_loss_generic(
    const float* __restrict__ ray_depth,
    const float* __restrict__ z_vals,
    const float* __restrict__ weights,
    const int*   __restrict__ ray_mask,
    float* __restrict__ partials,
    int n_rays, int S)
{
    const int wave = threadIdx.x >> 6;
    const int lane = threadIdx.x & 63;
    const int r = blockIdx.x * 4 + wave;
    if (r >= n_rays) return;

    const float d  = ray_depth[r];
    const float lo = d - EPSILON;
    const float hi = d + EPSILON;

    float empty = 0.0f, wnear = 0.0f;
    const float* zr = z_vals  + (size_t)r * S;
    const float* wr = weights + (size_t)r * S;
    for (int k = lane; k < S; k += 64) {
        const float z = zr[k];
        const float w = wr[k];
        empty += (z < lo) ? w * w : 0.0f;
        wnear += (z >= lo && z < hi) ? w : 0.0f;
    }
    #pragma unroll
    for (int off = 32; off > 0; off >>= 1) {
        empty += __shfl_down(empty, off, 64);
        wnear += __shfl_down(wnear, off, 64);
    }
    if (lane == 0 && ray_mask[r] != 0) {
        const int slot = r & (NSLOTS - 1);
        const float t = 1.0f - wnear;
        atomicAdd(&partials[slot],              empty);
        atomicAdd(&partials[NSLOTS + slot],     t * t);
        atomicAdd(&partials[2 * NSLOTS + slot], 1.0f);
    }
}

__global__ void sight_near_finalize_kernel(
    const float* __restrict__ partials, float* __restrict__ out)
{
    const int lane = threadIdx.x;  // 64 threads
    float e = partials[lane];
    float n = partials[NSLOTS + lane];
    float m = partials[2 * NSLOTS + lane];
    #pragma unroll
    for (int off = 32; off > 0; off >>= 1) {
        e += __shfl_down(e, off, 64);
        n += __shfl_down(n, off, 64);
        m += __shfl_down(m, off, 64);
    }
    if (lane == 0) {
        out[0] = e / m;   // loss_empty
        out[1] = n / m;   // loss_near
    }
}

extern "C" void kernel_launch(void* const* d_in, const int* in_sizes, int n_in,
                              void* d_out, int out_size, void* d_ws, size_t ws_size,
                              hipStream_t stream) {
    const float* ray_depth = (const float*)d_in[0];
    const float* z_vals    = (const float*)d_in[1];
    const float* weights   = (const float*)d_in[2];
    const int*   ray_mask  = (const int*)d_in[3];

    const int n_rays = in_sizes[0];                // ray_depth is [N,1]
    const int S      = in_sizes[1] / n_rays;       // 1024

    float* partials = (float*)d_ws;
    hipMemsetAsync(partials, 0, 3 * NSLOTS * sizeof(float), stream);

    const int blocks = (n_rays + 3) / 4;           // 4 waves per block
    if (S == 1024) {
        sight_near_loss_kernel<1024><<<blocks, 256, 0, stream>>>(
            ray_depth, z_vals, weights, ray_mask, partials, n_rays);
    } else {
        sight_near_loss_generic<<<blocks, 256, 0, stream>>>(
            ray_depth, z_vals, weights, ray_mask, partials, n_rays, S);
    }
    sight_near_finalize_kernel<<<1, 64, 0, stream>>>(partials, (float*)d_out);
}

// Round 3
// 156.675 us; speedup vs baseline: 1.1461x; 1.0685x over previous
//
#include <hip/hip_runtime.h>

#define EPSILON 0.05f
#define NSLOTS 64

// Persistent-ish waves: each 64-lane wave processes RPW consecutive rays with
// double-buffered register prefetch, so the wave always has ~8
// global_load_dwordx4 in flight and never drains vmcnt to 0 between rays.
// depth/mask for all RPW rays are hoisted to wave start (kills the serialized
// tail round-trips of the 1-ray-per-wave version). One atomic triple per wave.
template <int S, int RPW>
__global__ __launch_bounds__(256) void sight_near_loss_kernel(
    const float* __restrict__ ray_depth,   // [N]
    const float* __restrict__ z_vals,      // [N, S]
    const float* __restrict__ weights,     // [N, S]
    const int*   __restrict__ ray_mask,    // [N]
    float* __restrict__ partials,          // [3*NSLOTS]
    int n_rays)
{
    const int lane    = threadIdx.x & 63;
    const int wave_id = (blockIdx.x * blockDim.x + threadIdx.x) >> 6;
    const int r0      = wave_id * RPW;
    if (r0 >= n_rays) return;

    constexpr int PER = S / 4 / 64;   // float4 per lane per stream (4 for S=1024)

    float4 zb[2][PER], wb[2][PER];
    float  dep[RPW];
    float  fm[RPW];

    // hoist per-ray scalars for all RPW rays (oldest in vmcnt order -> free)
    #pragma unroll
    for (int i = 0; i < RPW; ++i) {
        const int r = r0 + i;
        dep[i] = (r < n_rays) ? ray_depth[r] : 0.0f;
        fm[i]  = (r < n_rays && ray_mask[r] != 0) ? 1.0f : 0.0f;
    }

    // prime buffer 0 with ray r0
    {
        const float4* z4 = (const float4*)(z_vals  + (size_t)r0 * S);
        const float4* w4 = (const float4*)(weights + (size_t)r0 * S);
        #pragma unroll
        for (int k = 0; k < PER; ++k) { zb[0][k] = z4[lane + 64 * k]; }
        #pragma unroll
        for (int k = 0; k < PER; ++k) { wb[0][k] = w4[lane + 64 * k]; }
    }

    float e_lane = 0.0f;   // per-lane masked sum of w^2 (reduced once at end)
    float n_acc  = 0.0f;   // (1 - w_near)^2 accumulator (uniform across lanes)
    float m_acc  = 0.0f;   // masked-ray count

    #pragma unroll
    for (int i = 0; i < RPW; ++i) {
        const int cur = i & 1, nxt = cur ^ 1;
        // prefetch next ray while computing current
        if (i + 1 < RPW) {
            const int rn = (r0 + i + 1 < n_rays) ? (r0 + i + 1) : r0;
            const float4* z4 = (const float4*)(z_vals  + (size_t)rn * S);
            const float4* w4 = (const float4*)(weights + (size_t)rn * S);
            #pragma unroll
            for (int k = 0; k < PER; ++k) { zb[nxt][k] = z4[lane + 64 * k]; }
            #pragma unroll
            for (int k = 0; k < PER; ++k) { wb[nxt][k] = w4[lane + 64 * k]; }
        }

        const float lo = dep[i] - EPSILON;
        const float hi = dep[i] + EPSILON;
        float emp = 0.0f, wnr = 0.0f;
        #pragma unroll
        for (int k = 0; k < PER; ++k) {
            const float4 z = zb[cur][k];
            const float4 w = wb[cur][k];
            emp += (z.x < lo) ? w.x * w.x : 0.0f;
            emp += (z.y < lo) ? w.y * w.y : 0.0f;
            emp += (z.z < lo) ? w.z * w.z : 0.0f;
            emp += (z.w < lo) ? w.w * w.w : 0.0f;
            wnr += (z.x >= lo && z.x < hi) ? w.x : 0.0f;
            wnr += (z.y >= lo && z.y < hi) ? w.y : 0.0f;
            wnr += (z.z >= lo && z.z < hi) ? w.z : 0.0f;
            wnr += (z.w >= lo && z.w < hi) ? w.w : 0.0f;
        }

        e_lane += fm[i] * emp;

        // butterfly: all lanes end with the full per-ray sum (no divergence)
        #pragma unroll
        for (int off = 32; off > 0; off >>= 1) wnr += __shfl_xor(wnr, off, 64);
        const float t = 1.0f - wnr;
        n_acc += fm[i] * t * t;
        m_acc += fm[i];
    }

    #pragma unroll
    for (int off = 32; off > 0; off >>= 1) e_lane += __shfl_xor(e_lane, off, 64);

    if (lane == 0) {
        const int slot = wave_id & (NSLOTS - 1);
        atomicAdd(&partials[slot],              e_lane);
        atomicAdd(&partials[NSLOTS + slot],     n_acc);
        atomicAdd(&partials[2 * NSLOTS + slot], m_acc);
    }
}

// Generic fallback (runtime S)
__global__ __launch_bounds__(256) void sight_near_loss_generic(
    const float* __restrict__ ray_depth,
    const float* __restrict__ z_vals,
    const float* __restrict__ weights,
    const int*   __restrict__ ray_mask,
    float* __restrict__ partials,
    int n_rays, int S)
{
    const int wave = threadIdx.x >> 6;
    const int lane = threadIdx.x & 63;
    const int r = blockIdx.x * 4 + wave;
    if (r >= n_rays) return;

    const float d  = ray_depth[r];
    const float lo = d - EPSILON;
    const float hi = d + EPSILON;

    float empty = 0.0f, wnear = 0.0f;
    const float* zr = z_vals  + (size_t)r * S;
    const float* wr = weights + (size_t)r * S;
    for (int k = lane; k < S; k += 64) {
        const float z = zr[k];
        const float w = wr[k];
        empty += (z < lo) ? w * w : 0.0f;
        wnear += (z >= lo && z < hi) ? w : 0.0f;
    }
    #pragma unroll
    for (int off = 32; off > 0; off >>= 1) {
        empty += __shfl_xor(empty, off, 64);
        wnear += __shfl_xor(wnear, off, 64);
    }
    if (lane == 0 && ray_mask[r] != 0) {
        const int slot = r & (NSLOTS - 1);
        const float t = 1.0f - wnear;
        atomicAdd(&partials[slot],              empty);
        atomicAdd(&partials[NSLOTS + slot],     t * t);
        atomicAdd(&partials[2 * NSLOTS + slot], 1.0f);
    }
}

__global__ void sight_near_finalize_kernel(
    const float* __restrict__ partials, float* __restrict__ out)
{
    const int lane = threadIdx.x;  // 64 threads
    float e = partials[lane];
    float n = partials[NSLOTS + lane];
    float m = partials[2 * NSLOTS + lane];
    #pragma unroll
    for (int off = 32; off > 0; off >>= 1) {
        e += __shfl_xor(e, off, 64);
        n += __shfl_xor(n, off, 64);
        m += __shfl_xor(m, off, 64);
    }
    if (lane == 0) {
        out[0] = e / m;   // loss_empty
        out[1] = n / m;   // loss_near
    }
}

extern "C" void kernel_launch(void* const* d_in, const int* in_sizes, int n_in,
                              void* d_out, int out_size, void* d_ws, size_t ws_size,
                              hipStream_t stream) {
    const float* ray_depth = (const float*)d_in[0];
    const float* z_vals    = (const float*)d_in[1];
    const float* weights   = (const float*)d_in[2];
    const int*   ray_mask  = (const int*)d_in[3];

    const int n_rays = in_sizes[0];                // ray_depth is [N,1]
    const int S      = in_sizes[1] / n_rays;       // 1024

    float* partials = (float*)d_ws;
    hipMemsetAsync(partials, 0, 3 * NSLOTS * sizeof(float), stream);

    if (S == 1024) {
        constexpr int RPW = 4;
        const int waves  = (n_rays + RPW - 1) / RPW;
        const int blocks = (waves + 3) / 4;        // 4 waves per block
        sight_near_loss_kernel<1024, RPW><<<blocks, 256, 0, stream>>>(
            ray_depth, z_vals, weights, ray_mask, partials, n_rays);
    } else {
        const int blocks = (n_rays + 3) / 4;
        sight_near_loss_generic<<<blocks, 256, 0, stream>>>(
            ray_depth, z_vals, weights, ray_mask, partials, n_rays, S);
    }
    sight_near_finalize_kernel<<<1, 64, 0, stream>>>(partials, (float*)d_out);
}